// Round 12
// baseline (1357.732 us; speedup 1.0000x reference)
//
#include <hip/hip_runtime.h>
#include <hip/hip_bf16.h>

// MultiTokenPrediction: main head logits + fused CE for main + 2 aux heads.
// B=1, S=2048, D=1024, V=50257, heads predict t+1 (main), t+2, t+3 (aux).

typedef __hip_bfloat16 bf16;
typedef __attribute__((ext_vector_type(8))) short bf16x8;
typedef __attribute__((ext_vector_type(4))) float f32x4;

typedef const __attribute__((address_space(1))) void* gptr_t;
typedef __attribute__((address_space(3))) void* lptr_t;

#define S_LEN   2048
#define DMODEL  1024
#define VOCAB   50257
#define NT128   393
#define NBLK    6288    // 8*49*16 + 16

__device__ __forceinline__ void gload_lds16(const void* g, void* l) {
  __builtin_amdgcn_global_load_lds((gptr_t)g, (lptr_t)l, 16, 0, 0);
}

// ---------------- f32 -> bf16 conversion (small buffers only) ----------------
__global__ __launch_bounds__(256) void k_cvt(const float* __restrict__ src,
                                             bf16* __restrict__ dst,
                                             long rows_src, long rows_pad) {
  const long total4 = rows_pad << 8;
  for (long i = (long)blockIdx.x * 256 + threadIdx.x; i < total4;
       i += (long)gridDim.x * 256) {
    const long e = i << 2;
    const long row = e >> 10;
    alignas(8) bf16 o[4];
    if (row < rows_src) {
      const float4 v = *(const float4*)(src + e);
      o[0] = __float2bfloat16(v.x); o[1] = __float2bfloat16(v.y);
      o[2] = __float2bfloat16(v.z); o[3] = __float2bfloat16(v.w);
    } else {
      o[0] = o[1] = o[2] = o[3] = __float2bfloat16(0.f);
    }
    *(uint2*)(dst + e) = *(const uint2*)o;
  }
}

// ---------------- RMSNorm row kernel: f32 in, bf16 out ----------------
__global__ __launch_bounds__(256) void k_rms(const float* __restrict__ x,
                                             const float* __restrict__ w,
                                             bf16* __restrict__ xn) {
  const int row = blockIdx.x;
  const int t = threadIdx.x;
  const float4 v = ((const float4*)(x + (size_t)row * DMODEL))[t];
  float ss = v.x*v.x + v.y*v.y + v.z*v.z + v.w*v.w;
  #pragma unroll
  for (int d = 1; d < 64; d <<= 1) ss += __shfl_xor(ss, d, 64);
  __shared__ float red[4];
  if ((t & 63) == 0) red[t >> 6] = ss;
  __syncthreads();
  const float tot = red[0] + red[1] + red[2] + red[3];
  const float scale = rsqrtf(tot * (1.f / DMODEL) + 1e-5f);
  const float4 wv = ((const float4*)w)[t];
  alignas(8) bf16 o[4];
  o[0] = __float2bfloat16(v.x * scale * wv.x);
  o[1] = __float2bfloat16(v.y * scale * wv.y);
  o[2] = __float2bfloat16(v.z * scale * wv.z);
  o[3] = __float2bfloat16(v.w * scale * wv.w);
  *(uint2*)(xn + (size_t)row * DMODEL + t * 4) = *(const uint2*)o;
}

// ======== 128x128 MFMA GEMM, BK=64: A bf16 via DMA, B raw *f32* via reg-stage ========
// C[m][n] = sum_k A[m][k]*Bf[n][k]. Bf = RAW f32 weights (no cvt pass!).
// R11 measured: aux K-loop ~211us (~1020 TF), conflicts 0. This round deletes
// the 3x ~52us serial W-cvt dispatches: per K-step each thread COOPERATIVELY
// loads 128B of B f32 (no duplication; R9's mistake was per-wave-private 2x),
// converts to bf16 in regs, ds_write_b128 into the SAME swizzled bf16 LDS
// layout R11's verified frag reads use (LDS read BW unchanged; R8's mistake
// was f32-in-LDS 2x read bytes). B loads prefetched one full K-step ahead
// (>600cyc > L2 latency). vmcnt: issue B(k),A(k) -> vmcnt(4) [B in regs,
// A flying] -> cvt+ds_write -> issue B(k+1) -> vmcnt(8)+lgkmcnt(0) -> barrier
// -> 32 MFMA. Write-conflict softened by per-row chunk rotation applied via
// ADDRESSES (data indices compile-time; rule #20). OOB rows clamp to VOCAB-1
// (cols >= Nvalid masked in CE/C-write, verified R8). A path R11-identical.
template<bool WRITE_OUT>
__global__ __launch_bounds__(256, 2)
void k_gemm128(const bf16* __restrict__ A, const float* __restrict__ Bf,
               float* __restrict__ C, long ldc, int Nvalid,
               const int* __restrict__ targets, int shift,
               float* __restrict__ pmax, float* __restrict__ psum,
               float* __restrict__ ptgt, int ntiles) {
  __shared__ bf16 As[2][128 * 32];   // k-half 0 / 1, each 8 subtiles of [16][32]
  __shared__ bf16 Bs[2][128 * 32];
  __shared__ float lds_m[128][2];
  __shared__ float lds_s[128][2];
  __shared__ int lds_tgt[128];

  const int t = threadIdx.x;
  const int w = t >> 6, l = t & 63, g = l >> 4, q = l & 15;
  const int wr = w >> 1, wc = w & 1;
  const int id = blockIdx.x;
  int bm, bn;
  if (id < 6272) {
    const int x = id & 7, u = id >> 3;
    bm = u & 15;
    bn = x * 49 + (u >> 4);
  } else {
    bm = id - 6272;
    bn = 392;
  }

  f32x4 acc[4][4];
  #pragma unroll
  for (int i = 0; i < 4; ++i)
    #pragma unroll
    for (int j = 0; j < 4; ++j)
      #pragma unroll
      for (int r = 0; r < 4; ++r) acc[i][j][r] = 0.f;

  // ---- A staging (R11-identical: DMA, pre-swizzled source col) ----
  char* dA = (char*)As + w * 1024;
  const int scol = ((t & 3) * 16) ^ (((t >> 5) & 1) * 32);
  const char* gA0 = (const char*)(A + (size_t)(bm * 128 + (t >> 2)) * DMODEL) + scol;
  const char* gA1 = gA0 + (size_t)64 * DMODEL * 2;

  // ---- B f32 cooperative reg-staging ----
  // thread t: row r_=t&127 of the B tile, k-half h_=t>>7 (32 f32 cols = 128B).
  const int r_ = t & 127;
  const int h_ = t >> 7;
  int brow = bn * 128 + r_;
  if (brow > VOCAB - 1) brow = VOCAB - 1;
  const char* gBf = (const char*)(Bf + (size_t)brow * DMODEL + h_ * 32);
  const int rr_ = r_ & 15;
  char* wB = (char*)Bs + h_ * 8192 + (r_ >> 4) * 1024 + rr_ * 64;
  const int xorb = ((rr_ >> 3) & 1) << 5;
  const int rot = (r_ >> 1) & 3;
  int boff[4];   // f32 byte offset of chunk slot j (rotated); bf16 byte = >>1
  #pragma unroll
  for (int j = 0; j < 4; ++j) boff[j] = ((j + rot) & 3) * 32;

  // ---- frag-read bases (st_16x32-swizzled; verified conflict-free R3/R10) ----
  const int laneoff = (q * 64 + g * 16) ^ (((q >> 3) & 1) << 5);
  const char* rdA = (const char*)As + wr * 4096 + laneoff;
  const char* rdB = (const char*)Bs + wc * 4096 + laneoff;

  // ---- prologue: load B(0) into regs ----
  float4 bv0[4], bv1[4];
  #pragma unroll
  for (int j = 0; j < 4; ++j) {
    bv0[j] = *(const float4*)(gBf + boff[j]);
    bv1[j] = *(const float4*)(gBf + boff[j] + 16);
  }

  #pragma unroll
  for (int k0 = 0; k0 < 16; ++k0) {
    const int kb = k0 * 128;
    // A DMA (4 ops; LDS free after previous trailing barrier)
    gload_lds16(gA0 + kb, dA);
    gload_lds16(gA1 + kb, dA + 4096);
    gload_lds16(gA0 + kb + 64, dA + 8192);
    gload_lds16(gA1 + kb + 64, dA + 12288);
    // B(k0) regs ready? (B issued before A -> oldest 8; vmcnt(4) = B done)
    asm volatile("s_waitcnt vmcnt(4)" ::: "memory");
    // cvt + swizzled ds_write (data indices static; addresses carry rotation)
    #pragma unroll
    for (int j = 0; j < 4; ++j) {
      alignas(16) bf16 c8[8];
      c8[0] = __float2bfloat16(bv0[j].x); c8[1] = __float2bfloat16(bv0[j].y);
      c8[2] = __float2bfloat16(bv0[j].z); c8[3] = __float2bfloat16(bv0[j].w);
      c8[4] = __float2bfloat16(bv1[j].x); c8[5] = __float2bfloat16(bv1[j].y);
      c8[6] = __float2bfloat16(bv1[j].z); c8[7] = __float2bfloat16(bv1[j].w);
      *(bf16x8*)(wB + ((boff[j] >> 1) ^ xorb)) = *(const bf16x8*)c8;
    }
    // prefetch B(k0+1) (8 ops), then drain A(k0) + make ds_writes visible
    if (k0 < 15) {
      const int nb = (k0 + 1) * 256;
      #pragma unroll
      for (int j = 0; j < 4; ++j) {
        bv0[j] = *(const float4*)(gBf + nb + boff[j]);
        bv1[j] = *(const float4*)(gBf + nb + boff[j] + 16);
      }
      asm volatile("s_waitcnt vmcnt(8) lgkmcnt(0)" ::: "memory");
    } else {
      asm volatile("s_waitcnt vmcnt(0) lgkmcnt(0)" ::: "memory");
    }
    __builtin_amdgcn_s_barrier();

    bf16x8 a[4], b[4];
    // ---- k-half 0 ----
    #pragma unroll
    for (int mi = 0; mi < 4; ++mi) a[mi] = *(const bf16x8*)(rdA + mi * 1024);
    #pragma unroll
    for (int ni = 0; ni < 4; ++ni) b[ni] = *(const bf16x8*)(rdB + ni * 1024);
    __builtin_amdgcn_s_setprio(1);
    #pragma unroll
    for (int mi = 0; mi < 4; ++mi)
      #pragma unroll
      for (int ni = 0; ni < 4; ++ni)
        acc[mi][ni] = __builtin_amdgcn_mfma_f32_16x16x32_bf16(a[mi], b[ni], acc[mi][ni], 0, 0, 0);
    __builtin_amdgcn_s_setprio(0);
    // ---- k-half 1 ----
    #pragma unroll
    for (int mi = 0; mi < 4; ++mi) a[mi] = *(const bf16x8*)(rdA + 8192 + mi * 1024);
    #pragma unroll
    for (int ni = 0; ni < 4; ++ni) b[ni] = *(const bf16x8*)(rdB + 8192 + ni * 1024);
    __builtin_amdgcn_s_setprio(1);
    #pragma unroll
    for (int mi = 0; mi < 4; ++mi)
      #pragma unroll
      for (int ni = 0; ni < 4; ++ni)
        acc[mi][ni] = __builtin_amdgcn_mfma_f32_16x16x32_bf16(a[mi], b[ni], acc[mi][ni], 0, 0, 0);
    __builtin_amdgcn_s_setprio(0);
    __builtin_amdgcn_s_barrier();
  }

  // ---------------- epilogue: C write (nontemporal) ----------------
  if constexpr (WRITE_OUT) {
    #pragma unroll
    for (int mi = 0; mi < 4; ++mi) {
      #pragma unroll
      for (int r = 0; r < 4; ++r) {
        const long row = bm * 128 + wr * 64 + mi * 16 + g * 4 + r;
        #pragma unroll
        for (int ni = 0; ni < 4; ++ni) {
          const int col = bn * 128 + wc * 64 + ni * 16 + q;
          if (col < Nvalid)
            __builtin_nontemporal_store(acc[mi][ni][r], &C[row * ldc + col]);
        }
      }
    }
  }

  // ---------------- fused CE partials ----------------
  if (t < 128) {
    const int rowg = bm * 128 + t;
    lds_tgt[t] = (rowg < S_LEN - shift) ? targets[rowg + shift] : -1;
  }
  __syncthreads();
  #pragma unroll
  for (int mi = 0; mi < 4; ++mi) {
    #pragma unroll
    for (int r = 0; r < 4; ++r) {
      const int rl = wr * 64 + mi * 16 + g * 4 + r;
      const int tgt = lds_tgt[rl];
      float v[4];
      #pragma unroll
      for (int ni = 0; ni < 4; ++ni) {
        const int n = bn * 128 + wc * 64 + ni * 16 + q;
        const float av = acc[mi][ni][r];
        if (n == tgt) ptgt[bm * 128 + rl] = av;
        v[ni] = (n < Nvalid) ? av : -1e30f;
      }
      float m = fmaxf(fmaxf(v[0], v[1]), fmaxf(v[2], v[3]));
      #pragma unroll
      for (int d = 1; d < 16; d <<= 1) m = fmaxf(m, __shfl_xor(m, d, 64));
      float s = 0.f;
      #pragma unroll
      for (int ni = 0; ni < 4; ++ni) s += __expf(v[ni] - m);
      #pragma unroll
      for (int d = 1; d < 16; d <<= 1) s += __shfl_xor(s, d, 64);
      if (q == 0) { lds_m[rl][wc] = m; lds_s[rl][wc] = s; }
    }
  }
  __syncthreads();
  if (t < 128) {
    const float m0 = lds_m[t][0], m1 = lds_m[t][1];
    const float s0 = lds_s[t][0], s1 = lds_s[t][1];
    const float M = fmaxf(m0, m1);
    const float Ssum = s0 * __expf(m0 - M) + s1 * __expf(m1 - M);
    const size_t idx = (size_t)(bm * 128 + t) * ntiles + bn;
    pmax[idx] = M;
    psum[idx] = Ssum;
  }
}

// ---------------- 128x128 GEMM (small d->d projection, bf16 B) ----------------
__global__ __launch_bounds__(256, 2)
void k_gemm(const bf16* __restrict__ A, const bf16* __restrict__ B,
            float* __restrict__ C, long ldc, int Nvalid) {
  constexpr int K = DMODEL;
  __shared__ bf16 As[128 * 32];
  __shared__ bf16 Bs[128 * 32];

  const int t = threadIdx.x;
  const int bn = blockIdx.x, bm = blockIdx.y;
  const int w = t >> 6, l = t & 63, g = l >> 4, q = l & 15;
  const int wr = w >> 1, wc = w & 1;

  f32x4 acc[4][4];
  #pragma unroll
  for (int i = 0; i < 4; ++i)
    #pragma unroll
    for (int j = 0; j < 4; ++j)
      #pragma unroll
      for (int r = 0; r < 4; ++r) acc[i][j][r] = 0.f;

  char* lA0 = (char*)As + w * 1024;
  char* lA1 = (char*)As + 4096 + w * 1024;
  char* lB0 = (char*)Bs + w * 1024;
  char* lB1 = (char*)Bs + 4096 + w * 1024;
  const char* gA0 = (const char*)(A + (size_t)(bm * 128 + (t >> 2)) * K) + (t & 3) * 16;
  const char* gA1 = gA0 + (size_t)64 * K * 2;
  const char* gB0 = (const char*)(B + (size_t)(bn * 128 + (t >> 2)) * K) + (t & 3) * 16;
  const char* gB1 = gB0 + (size_t)64 * K * 2;

  for (int k0 = 0; k0 < K; k0 += 32) {
    const int kb = k0 * 2;
    gload_lds16(gA0 + kb, lA0);
    gload_lds16(gA1 + kb, lA1);
    gload_lds16(gB0 + kb, lB0);
    gload_lds16(gB1 + kb, lB1);
    __syncthreads();
    bf16x8 a[4], b[4];
    #pragma unroll
    for (int mi = 0; mi < 4; ++mi)
      a[mi] = *(const bf16x8*)&As[(wr * 64 + mi * 16 + q) * 32 + g * 8];
    #pragma unroll
    for (int ni = 0; ni < 4; ++ni)
      b[ni] = *(const bf16x8*)&Bs[(wc * 64 + ni * 16 + q) * 32 + g * 8];
    #pragma unroll
    for (int mi = 0; mi < 4; ++mi)
      #pragma unroll
      for (int ni = 0; ni < 4; ++ni)
        acc[mi][ni] = __builtin_amdgcn_mfma_f32_16x16x32_bf16(a[mi], b[ni], acc[mi][ni], 0, 0, 0);
    __syncthreads();
  }

  #pragma unroll
  for (int mi = 0; mi < 4; ++mi) {
    #pragma unroll
    for (int r = 0; r < 4; ++r) {
      const long row = bm * 128 + wr * 64 + mi * 16 + g * 4 + r;
      #pragma unroll
      for (int ni = 0; ni < 4; ++ni) {
        const int col = bn * 128 + wc * 64 + ni * 16 + q;
        if (col < Nvalid) C[row * ldc + col] = acc[mi][ni][r];
      }
    }
  }
}

// ---------------- combine per-row partials -> NLL ----------------
__global__ __launch_bounds__(64) void k_combine(const float* __restrict__ pmax,
                                                const float* __restrict__ psum,
                                                const float* __restrict__ ptgt,
                                                float* __restrict__ nll,
                                                int ntiles, int nv) {
  const int r = blockIdx.x;
  const int l = threadIdx.x;
  float M = -1e30f, Ssum = 0.f;
  for (int tl = l; tl < ntiles; tl += 64) {
    const float m = pmax[(size_t)r * ntiles + tl];
    const float s = psum[(size_t)r * ntiles + tl];
    const float nM = fmaxf(M, m);
    Ssum = Ssum * __expf(M - nM) + s * __expf(m - nM);
    M = nM;
  }
  #pragma unroll
  for (int d = 1; d < 64; d <<= 1) {
    const float m2 = __shfl_xor(M, d, 64);
    const float s2 = __shfl_xor(Ssum, d, 64);
    const float nM = fmaxf(M, m2);
    Ssum = Ssum * __expf(M - nM) + s2 * __expf(m2 - nM);
    M = nM;
  }
  if (l == 0) nll[r] = (r < nv) ? (M + logf(Ssum) - ptgt[r]) : 0.f;
}

// ---------------- final loss ----------------
__global__ __launch_bounds__(256) void k_loss(const float* __restrict__ nll,
                                              float* __restrict__ out) {
  __shared__ float sh[256];
  const int t = threadIdx.x;
  float sums[3];
  #pragma unroll
  for (int h = 0; h < 3; ++h) {
    const int nv = 2047 - h;
    float s = 0.f;
    for (int r = t; r < nv; r += 256) s += nll[h * 2048 + r];
    sh[t] = s; __syncthreads();
    for (int off = 128; off > 0; off >>= 1) {
      if (t < off) sh[t] += sh[t + off];
      __syncthreads();
    }
    sums[h] = sh[0]; __syncthreads();
  }
  if (t == 0)
    out[0] = sums[0] / 2047.f + 0.3f * 0.5f * (sums[1] / 2046.f + sums[2] / 2045.f);
}

extern "C" void kernel_launch(void* const* d_in, const int* in_sizes, int n_in,
                              void* d_out, int out_size, void* d_ws, size_t ws_size,
                              hipStream_t stream) {
  const float* hidden      = (const float*)d_in[0];
  const int*   targets     = (const int*)d_in[1];
  const float* emb_w       = (const float*)d_in[2];
  const float* main_norm_w = (const float*)d_in[3];
  const float* aux_proj_w  = (const float*)d_in[4];
  const float* aux_norm_w  = (const float*)d_in[5];
  const float* aux_out_w   = (const float*)d_in[6];
  float* out = (float*)d_out;

  char* ws = (char*)d_ws;
  bf16*  hb    = (bf16*)(ws);                   // hidden bf16, 4 MiB
  bf16*  xn    = (bf16*)(ws + 4194304);         // normalized input bf16, 4 MiB
  bf16*  projb = (bf16*)(ws + 8388608);         // aux proj weights bf16, 4 MiB
  float* hbuf  = (float*)(ws + 12582912);       // aux pre-norm f32, 8 MiB
  float* pmax  = (float*)(ws + 20971520);       // [2048][393] f32
  float* psum  = (float*)(ws + 24248320);       // [2048][393] f32
  float* ptgt  = (float*)(ws + 27525120);       // [2048]
  float* nll   = (float*)(ws + 27533312);       // [3][2048]

  // prep (small buffers only; big W matrices read as raw f32 by the GEMM)
  k_cvt<<<2048, 256, 0, stream>>>(hidden, hb, 2048, 2048);
  k_cvt<<<2048, 256, 0, stream>>>(aux_proj_w, projb, 2048, 2048);
  k_rms<<<2048, 256, 0, stream>>>(hidden, main_norm_w, xn);

  // ---- main head ----
  k_gemm128<true><<<NBLK, 256, 0, stream>>>(
      xn, emb_w, out, VOCAB, VOCAB, targets, 1, pmax, psum, ptgt, NT128);
  k_combine<<<2048, 64, 0, stream>>>(pmax, psum, ptgt, nll, NT128, 2047);

  // ---- aux heads ----
  for (int i = 0; i < 2; ++i) {
    k_gemm<<<dim3(8, 16), 256, 0, stream>>>(
        hb, projb + (size_t)i * DMODEL * DMODEL, hbuf, DMODEL, DMODEL);
    k_rms<<<2048, 256, 0, stream>>>(hbuf, aux_norm_w + (size_t)i * DMODEL, xn);
    k_gemm128<false><<<NBLK, 256, 0, stream>>>(
        xn, aux_out_w + (size_t)i * VOCAB * DMODEL, nullptr, 0, VOCAB,
        targets, i + 2, pmax, psum, ptgt, NT128);
    k_combine<<<2048, 64, 0, stream>>>(pmax, psum, ptgt, nll + (i + 1) * 2048, NT128, 2048 - (i + 2));
  }

  k_loss<<<1, 256, 0, stream>>>(nll, out + (size_t)S_LEN * VOCAB);
}

// Round 13
// 1086.172 us; speedup vs baseline: 1.2500x; 1.2500x over previous
//
#include <hip/hip_runtime.h>
#include <hip/hip_bf16.h>

// MultiTokenPrediction: main head logits + fused CE for main + 2 aux heads.
// B=1, S=2048, D=1024, V=50257, heads predict t+1 (main), t+2, t+3 (aux).

typedef __hip_bfloat16 bf16;
typedef __attribute__((ext_vector_type(8))) short bf16x8;
typedef __attribute__((ext_vector_type(4))) float f32x4;

typedef const __attribute__((address_space(1))) void* gptr_t;
typedef __attribute__((address_space(3))) void* lptr_t;

#define S_LEN   2048
#define DMODEL  1024
#define VOCAB   50257
#define NPADR   50304   // 393*128 padded rows for Wb
#define NT128   393
#define NBLK    6288    // 8*49*16 + 16

__device__ __forceinline__ void gload_lds16(const void* g, void* l) {
  __builtin_amdgcn_global_load_lds((gptr_t)g, (lptr_t)l, 16, 0, 0);
}

// ---------------- f32 -> bf16 conversion with row zero-padding ----------------
__global__ __launch_bounds__(256) void k_cvt(const float* __restrict__ src,
                                             bf16* __restrict__ dst,
                                             long rows_src, long rows_pad) {
  const long total4 = rows_pad << 8;
  for (long i = (long)blockIdx.x * 256 + threadIdx.x; i < total4;
       i += (long)gridDim.x * 256) {
    const long e = i << 2;
    const long row = e >> 10;
    alignas(8) bf16 o[4];
    if (row < rows_src) {
      const float4 v = *(const float4*)(src + e);
      o[0] = __float2bfloat16(v.x); o[1] = __float2bfloat16(v.y);
      o[2] = __float2bfloat16(v.z); o[3] = __float2bfloat16(v.w);
    } else {
      o[0] = o[1] = o[2] = o[3] = __float2bfloat16(0.f);
    }
    *(uint2*)(dst + e) = *(const uint2*)o;
  }
}

// ------- fused prep: hidden f32 -> hb bf16 AND rmsnorm(hidden)*w -> xn bf16 -------
__global__ __launch_bounds__(256) void k_prep(const float* __restrict__ x,
                                              const float* __restrict__ w,
                                              bf16* __restrict__ hb,
                                              bf16* __restrict__ xn) {
  const int row = blockIdx.x;
  const int t = threadIdx.x;
  const float4 v = ((const float4*)(x + (size_t)row * DMODEL))[t];
  // raw bf16 copy
  alignas(8) bf16 h[4];
  h[0] = __float2bfloat16(v.x); h[1] = __float2bfloat16(v.y);
  h[2] = __float2bfloat16(v.z); h[3] = __float2bfloat16(v.w);
  *(uint2*)(hb + (size_t)row * DMODEL + t * 4) = *(const uint2*)h;
  // rmsnorm
  float ss = v.x*v.x + v.y*v.y + v.z*v.z + v.w*v.w;
  #pragma unroll
  for (int d = 1; d < 64; d <<= 1) ss += __shfl_xor(ss, d, 64);
  __shared__ float red[4];
  if ((t & 63) == 0) red[t >> 6] = ss;
  __syncthreads();
  const float tot = red[0] + red[1] + red[2] + red[3];
  const float scale = rsqrtf(tot * (1.f / DMODEL) + 1e-5f);
  const float4 wv = ((const float4*)w)[t];
  alignas(8) bf16 o[4];
  o[0] = __float2bfloat16(v.x * scale * wv.x);
  o[1] = __float2bfloat16(v.y * scale * wv.y);
  o[2] = __float2bfloat16(v.z * scale * wv.z);
  o[3] = __float2bfloat16(v.w * scale * wv.w);
  *(uint2*)(xn + (size_t)row * DMODEL + t * 4) = *(const uint2*)o;
}

// ---------------- RMSNorm row kernel: f32 in, bf16 out ----------------
__global__ __launch_bounds__(256) void k_rms(const float* __restrict__ x,
                                             const float* __restrict__ w,
                                             bf16* __restrict__ xn) {
  const int row = blockIdx.x;
  const int t = threadIdx.x;
  const float4 v = ((const float4*)(x + (size_t)row * DMODEL))[t];
  float ss = v.x*v.x + v.y*v.y + v.z*v.z + v.w*v.w;
  #pragma unroll
  for (int d = 1; d < 64; d <<= 1) ss += __shfl_xor(ss, d, 64);
  __shared__ float red[4];
  if ((t & 63) == 0) red[t >> 6] = ss;
  __syncthreads();
  const float tot = red[0] + red[1] + red[2] + red[3];
  const float scale = rsqrtf(tot * (1.f / DMODEL) + 1e-5f);
  const float4 wv = ((const float4*)w)[t];
  alignas(8) bf16 o[4];
  o[0] = __float2bfloat16(v.x * scale * wv.x);
  o[1] = __float2bfloat16(v.y * scale * wv.y);
  o[2] = __float2bfloat16(v.z * scale * wv.z);
  o[3] = __float2bfloat16(v.w * scale * wv.w);
  *(uint2*)(xn + (size_t)row * DMODEL + t * 4) = *(const uint2*)o;
}

// ======== 128x128 bf16 MFMA GEMM (R11 winner, plain C stores) ========
// C[m][n] = sum_k A[m][k]*B[n][k]. A:[2048][1024], B:[NPADR][1024] bf16.
// BK=64 (16 steps x 32 MFMA, 2 barriers/step; R11: aux 270->211us, ~1020 TF).
// Grid 6288, non-uniform XCD map (ids<6272: xcd=id&7 owns 49 bn x16 bm; tail
// 16 ids cover bn=392). st_16x32 swizzle both-sides (conflicts=0, R3/R10).
// C stores are PLAIN (not nontemporal): ldc=50257 rows have partial 64B
// lines; XCD-local bn-neighbors merge partials in L2 (R10 WRITE 464MB vs
// R11 nt 600MB). CE partials fused in epilogue.
template<bool WRITE_OUT>
__global__ __launch_bounds__(256, 2)
void k_gemm128(const bf16* __restrict__ A, const bf16* __restrict__ B,
               float* __restrict__ C, long ldc, int Nvalid,
               const int* __restrict__ targets, int shift,
               float* __restrict__ pmax, float* __restrict__ psum,
               float* __restrict__ ptgt, int ntiles) {
  __shared__ bf16 As[2][128 * 32];   // k-half 0 / 1, each 8 subtiles of [16][32]
  __shared__ bf16 Bs[2][128 * 32];
  __shared__ float lds_m[128][2];
  __shared__ float lds_s[128][2];
  __shared__ int lds_tgt[128];

  const int t = threadIdx.x;
  const int w = t >> 6, l = t & 63, g = l >> 4, q = l & 15;
  const int wr = w >> 1, wc = w & 1;
  const int id = blockIdx.x;
  int bm, bn;
  if (id < 6272) {
    const int x = id & 7, u = id >> 3;
    bm = u & 15;
    bn = x * 49 + (u >> 4);
  } else {
    bm = id - 6272;
    bn = 392;
  }

  f32x4 acc[4][4];
  #pragma unroll
  for (int i = 0; i < 4; ++i)
    #pragma unroll
    for (int j = 0; j < 4; ++j)
      #pragma unroll
      for (int r = 0; r < 4; ++r) acc[i][j][r] = 0.f;

  // staging dests (linear; wave w fills subtiles w and 4+w of each half-array)
  char* dA = (char*)As + w * 1024;
  char* dB = (char*)Bs + w * 1024;
  // global sources, col pre-swizzled (bytes within the 64-byte k-half row)
  const int scol = ((t & 3) * 16) ^ (((t >> 5) & 1) * 32);
  const char* gA0 = (const char*)(A + (size_t)(bm * 128 + (t >> 2)) * DMODEL) + scol;
  const char* gA1 = gA0 + (size_t)64 * DMODEL * 2;
  const char* gB0 = (const char*)(B + (size_t)(bn * 128 + (t >> 2)) * DMODEL) + scol;
  const char* gB1 = gB0 + (size_t)64 * DMODEL * 2;

  // frag-read bases (st_16x32-swizzled; verified conflict-free R3/R10)
  const int laneoff = (q * 64 + g * 16) ^ (((q >> 3) & 1) << 5);
  const char* rdA = (const char*)As + wr * 4096 + laneoff;
  const char* rdB = (const char*)Bs + wc * 4096 + laneoff;

  for (int k0 = 0; k0 < 16; ++k0) {
    const int kb = k0 * 128;         // byte offset of this 64-col K-step
    gload_lds16(gA0 + kb, dA);
    gload_lds16(gA1 + kb, dA + 4096);
    gload_lds16(gA0 + kb + 64, dA + 8192);
    gload_lds16(gA1 + kb + 64, dA + 12288);
    gload_lds16(gB0 + kb, dB);
    gload_lds16(gB1 + kb, dB + 4096);
    gload_lds16(gB0 + kb + 64, dB + 8192);
    gload_lds16(gB1 + kb + 64, dB + 12288);
    __syncthreads();
    bf16x8 a[4], b[4];
    // ---- k-half 0 ----
    #pragma unroll
    for (int mi = 0; mi < 4; ++mi) a[mi] = *(const bf16x8*)(rdA + mi * 1024);
    #pragma unroll
    for (int ni = 0; ni < 4; ++ni) b[ni] = *(const bf16x8*)(rdB + ni * 1024);
    __builtin_amdgcn_s_setprio(1);
    #pragma unroll
    for (int mi = 0; mi < 4; ++mi)
      #pragma unroll
      for (int ni = 0; ni < 4; ++ni)
        acc[mi][ni] = __builtin_amdgcn_mfma_f32_16x16x32_bf16(a[mi], b[ni], acc[mi][ni], 0, 0, 0);
    __builtin_amdgcn_s_setprio(0);
    // ---- k-half 1 ----
    #pragma unroll
    for (int mi = 0; mi < 4; ++mi) a[mi] = *(const bf16x8*)(rdA + 8192 + mi * 1024);
    #pragma unroll
    for (int ni = 0; ni < 4; ++ni) b[ni] = *(const bf16x8*)(rdB + 8192 + ni * 1024);
    __builtin_amdgcn_s_setprio(1);
    #pragma unroll
    for (int mi = 0; mi < 4; ++mi)
      #pragma unroll
      for (int ni = 0; ni < 4; ++ni)
        acc[mi][ni] = __builtin_amdgcn_mfma_f32_16x16x32_bf16(a[mi], b[ni], acc[mi][ni], 0, 0, 0);
    __builtin_amdgcn_s_setprio(0);
    __syncthreads();
  }

  // ---------------- epilogue: C write (plain stores; L2 merges partials) ----------------
  if constexpr (WRITE_OUT) {
    #pragma unroll
    for (int mi = 0; mi < 4; ++mi) {
      #pragma unroll
      for (int r = 0; r < 4; ++r) {
        const long row = bm * 128 + wr * 64 + mi * 16 + g * 4 + r;
        #pragma unroll
        for (int ni = 0; ni < 4; ++ni) {
          const int col = bn * 128 + wc * 64 + ni * 16 + q;
          if (col < Nvalid) C[row * ldc + col] = acc[mi][ni][r];
        }
      }
    }
  }

  // ---------------- fused CE partials ----------------
  if (t < 128) {
    const int rowg = bm * 128 + t;
    lds_tgt[t] = (rowg < S_LEN - shift) ? targets[rowg + shift] : -1;
  }
  __syncthreads();
  #pragma unroll
  for (int mi = 0; mi < 4; ++mi) {
    #pragma unroll
    for (int r = 0; r < 4; ++r) {
      const int rl = wr * 64 + mi * 16 + g * 4 + r;
      const int tgt = lds_tgt[rl];
      float v[4];
      #pragma unroll
      for (int ni = 0; ni < 4; ++ni) {
        const int n = bn * 128 + wc * 64 + ni * 16 + q;
        const float av = acc[mi][ni][r];
        if (n == tgt) ptgt[bm * 128 + rl] = av;
        v[ni] = (n < Nvalid) ? av : -1e30f;
      }
      float m = fmaxf(fmaxf(v[0], v[1]), fmaxf(v[2], v[3]));
      #pragma unroll
      for (int d = 1; d < 16; d <<= 1) m = fmaxf(m, __shfl_xor(m, d, 64));
      float s = 0.f;
      #pragma unroll
      for (int ni = 0; ni < 4; ++ni) s += __expf(v[ni] - m);
      #pragma unroll
      for (int d = 1; d < 16; d <<= 1) s += __shfl_xor(s, d, 64);
      if (q == 0) { lds_m[rl][wc] = m; lds_s[rl][wc] = s; }
    }
  }
  __syncthreads();
  if (t < 128) {
    const float m0 = lds_m[t][0], m1 = lds_m[t][1];
    const float s0 = lds_s[t][0], s1 = lds_s[t][1];
    const float M = fmaxf(m0, m1);
    const float Ssum = s0 * __expf(m0 - M) + s1 * __expf(m1 - M);
    const size_t idx = (size_t)(bm * 128 + t) * ntiles + bn;
    pmax[idx] = M;
    psum[idx] = Ssum;
  }
}

// ---------------- 128x128 GEMM (small d->d projection) ----------------
__global__ __launch_bounds__(256, 2)
void k_gemm(const bf16* __restrict__ A, const bf16* __restrict__ B,
            float* __restrict__ C, long ldc, int Nvalid) {
  constexpr int K = DMODEL;
  __shared__ bf16 As[128 * 32];
  __shared__ bf16 Bs[128 * 32];

  const int t = threadIdx.x;
  const int bn = blockIdx.x, bm = blockIdx.y;
  const int w = t >> 6, l = t & 63, g = l >> 4, q = l & 15;
  const int wr = w >> 1, wc = w & 1;

  f32x4 acc[4][4];
  #pragma unroll
  for (int i = 0; i < 4; ++i)
    #pragma unroll
    for (int j = 0; j < 4; ++j)
      #pragma unroll
      for (int r = 0; r < 4; ++r) acc[i][j][r] = 0.f;

  char* lA0 = (char*)As + w * 1024;
  char* lA1 = (char*)As + 4096 + w * 1024;
  char* lB0 = (char*)Bs + w * 1024;
  char* lB1 = (char*)Bs + 4096 + w * 1024;
  const char* gA0 = (const char*)(A + (size_t)(bm * 128 + (t >> 2)) * K) + (t & 3) * 16;
  const char* gA1 = gA0 + (size_t)64 * K * 2;
  const char* gB0 = (const char*)(B + (size_t)(bn * 128 + (t >> 2)) * K) + (t & 3) * 16;
  const char* gB1 = gB0 + (size_t)64 * K * 2;

  for (int k0 = 0; k0 < K; k0 += 32) {
    const int kb = k0 * 2;
    gload_lds16(gA0 + kb, lA0);
    gload_lds16(gA1 + kb, lA1);
    gload_lds16(gB0 + kb, lB0);
    gload_lds16(gB1 + kb, lB1);
    __syncthreads();
    bf16x8 a[4], b[4];
    #pragma unroll
    for (int mi = 0; mi < 4; ++mi)
      a[mi] = *(const bf16x8*)&As[(wr * 64 + mi * 16 + q) * 32 + g * 8];
    #pragma unroll
    for (int ni = 0; ni < 4; ++ni)
      b[ni] = *(const bf16x8*)&Bs[(wc * 64 + ni * 16 + q) * 32 + g * 8];
    #pragma unroll
    for (int mi = 0; mi < 4; ++mi)
      #pragma unroll
      for (int ni = 0; ni < 4; ++ni)
        acc[mi][ni] = __builtin_amdgcn_mfma_f32_16x16x32_bf16(a[mi], b[ni], acc[mi][ni], 0, 0, 0);
    __syncthreads();
  }

  #pragma unroll
  for (int mi = 0; mi < 4; ++mi) {
    #pragma unroll
    for (int r = 0; r < 4; ++r) {
      const long row = bm * 128 + wr * 64 + mi * 16 + g * 4 + r;
      #pragma unroll
      for (int ni = 0; ni < 4; ++ni) {
        const int col = bn * 128 + wc * 64 + ni * 16 + q;
        if (col < Nvalid) C[row * ldc + col] = acc[mi][ni][r];
      }
    }
  }
}

// ---------------- combine per-row partials -> NLL ----------------
__global__ __launch_bounds__(64) void k_combine(const float* __restrict__ pmax,
                                                const float* __restrict__ psum,
                                                const float* __restrict__ ptgt,
                                                float* __restrict__ nll,
                                                int ntiles, int nv) {
  const int r = blockIdx.x;
  const int l = threadIdx.x;
  float M = -1e30f, Ssum = 0.f;
  for (int tl = l; tl < ntiles; tl += 64) {
    const float m = pmax[(size_t)r * ntiles + tl];
    const float s = psum[(size_t)r * ntiles + tl];
    const float nM = fmaxf(M, m);
    Ssum = Ssum * __expf(M - nM) + s * __expf(m - nM);
    M = nM;
  }
  #pragma unroll
  for (int d = 1; d < 64; d <<= 1) {
    const float m2 = __shfl_xor(M, d, 64);
    const float s2 = __shfl_xor(Ssum, d, 64);
    const float nM = fmaxf(M, m2);
    Ssum = Ssum * __expf(M - nM) + s2 * __expf(m2 - nM);
    M = nM;
  }
  if (l == 0) nll[r] = (r < nv) ? (M + logf(Ssum) - ptgt[r]) : 0.f;
}

// ---------------- final loss ----------------
__global__ __launch_bounds__(256) void k_loss(const float* __restrict__ nll,
                                              float* __restrict__ out) {
  __shared__ float sh[256];
  const int t = threadIdx.x;
  float sums[3];
  #pragma unroll
  for (int h = 0; h < 3; ++h) {
    const int nv = 2047 - h;
    float s = 0.f;
    for (int r = t; r < nv; r += 256) s += nll[h * 2048 + r];
    sh[t] = s; __syncthreads();
    for (int off = 128; off > 0; off >>= 1) {
      if (t < off) sh[t] += sh[t + off];
      __syncthreads();
    }
    sums[h] = sh[0]; __syncthreads();
  }
  if (t == 0)
    out[0] = sums[0] / 2047.f + 0.3f * 0.5f * (sums[1] / 2046.f + sums[2] / 2045.f);
}

extern "C" void kernel_launch(void* const* d_in, const int* in_sizes, int n_in,
                              void* d_out, int out_size, void* d_ws, size_t ws_size,
                              hipStream_t stream) {
  const float* hidden      = (const float*)d_in[0];
  const int*   targets     = (const int*)d_in[1];
  const float* emb_w       = (const float*)d_in[2];
  const float* main_norm_w = (const float*)d_in[3];
  const float* aux_proj_w  = (const float*)d_in[4];
  const float* aux_norm_w  = (const float*)d_in[5];
  const float* aux_out_w   = (const float*)d_in[6];
  float* out = (float*)d_out;

  char* ws = (char*)d_ws;
  bf16*  Wb    = (bf16*)(ws);                   // [NPADR][1024] bf16, 103,022,592 B
  bf16*  hb    = (bf16*)(ws + 104857600);       // hidden bf16, 4 MiB
  bf16*  xn    = (bf16*)(ws + 109051904);       // normalized input bf16, 4 MiB
  bf16*  projb = (bf16*)(ws + 113246208);       // aux proj weights bf16, 4 MiB
  float* hbuf  = (float*)(ws + 117440512);      // aux pre-norm f32, 8 MiB
  float* pmax  = (float*)(ws + 125829120);      // [2048][393] f32
  float* psum  = (float*)(ws + 129105920);      // [2048][393] f32
  float* ptgt  = (float*)(ws + 132382720);      // [2048]
  float* nll   = (float*)(ws + 132390912);      // [3][2048]

  // prep: hidden->hb + rmsnorm->xn fused; proj weights cvt
  k_prep<<<2048, 256, 0, stream>>>(hidden, main_norm_w, hb, xn);
  k_cvt<<<2048, 256, 0, stream>>>(aux_proj_w, projb, 2048, 2048);

  // ---- main head ----
  k_cvt<<<2048, 256, 0, stream>>>(emb_w, Wb, VOCAB, NPADR);
  k_gemm128<true><<<NBLK, 256, 0, stream>>>(
      xn, Wb, out, VOCAB, VOCAB, targets, 1, pmax, psum, ptgt, NT128);
  k_combine<<<2048, 64, 0, stream>>>(pmax, psum, ptgt, nll, NT128, 2047);

  // ---- aux heads ----
  for (int i = 0; i < 2; ++i) {
    k_cvt<<<2048, 256, 0, stream>>>(aux_out_w + (size_t)i * VOCAB * DMODEL, Wb, VOCAB, NPADR);
    k_gemm<<<dim3(8, 16), 256, 0, stream>>>(
        hb, projb + (size_t)i * DMODEL * DMODEL, hbuf, DMODEL, DMODEL);
    k_rms<<<2048, 256, 0, stream>>>(hbuf, aux_norm_w + (size_t)i * DMODEL, xn);
    k_gemm128<false><<<NBLK, 256, 0, stream>>>(
        xn, Wb, nullptr, 0, VOCAB, targets, i + 2, pmax, psum, ptgt, NT128);
    k_combine<<<2048, 64, 0, stream>>>(pmax, psum, ptgt, nll + (i + 1) * 2048, NT128, 2048 - (i + 2));
  }

  k_loss<<<1, 256, 0, stream>>>(nll, out + (size_t)S_LEN * VOCAB);
}